// Round 7
// baseline (1071.115 us; speedup 1.0000x reference)
//
#include <hip/hip_runtime.h>
#include <math.h>

#define NN 100000
#define EE 500000
#define ET 64
#define NPAD 500032          // 7813 * 64
#define NEB  7813
#define NNB  1563            // ceil(100000/64)

typedef __attribute__((ext_vector_type(8))) short short8;
typedef __attribute__((ext_vector_type(4))) float f32x4;

// LDS chunk swizzle: 16B chunks, XOR row&7 into chunk index (T2, §6 G4)
#define C32(row, ch) (((row)<<5) + ((ch) ^ ((row)&7)))           // [*][256] bf16 buffers
#define C16(row, ch) (((row)<<4) + ((ch) ^ ((row)&7)))           // [*][128] bf16 buffers
#define E16(row, col) ((C16((row),(col)>>3)<<3) + ((col)&7))

__device__ __forceinline__ f32x4 mfma16(short8 a, short8 b, f32x4 c){
    return __builtin_amdgcn_mfma_f32_16x16x32_bf16(a, b, c, 0, 0, 0);
}
__device__ __forceinline__ short f2bf(float f){
    union { float f; unsigned u; } v; v.f = f;
    unsigned r = v.u + 0x7fffu + ((v.u >> 16) & 1u);
    return (short)(r >> 16);
}
__device__ __forceinline__ float bf2f(short s){
    union { unsigned u; float f; } v; v.u = ((unsigned)(unsigned short)s) << 16;
    return v.f;
}
__device__ __forceinline__ short8 bfrag(const short* __restrict__ W, int K, int ct, int ks, int lane){
    return *(const short8*)(W + (long)(ct*16 + (lane&15))*K + ks*32 + (lane>>4)*8);
}
__device__ __forceinline__ float dot4f(float4 a, float4 b){
    return fmaf(a.x,b.x, fmaf(a.y,b.y, fmaf(a.z,b.z, a.w*b.w)));
}

// ---------------- Prep: convert needed weights to bf16 in ws ----------------
__global__ __launch_bounds__(256) void prep_kernel(
    const float* __restrict__ q_w, const float* __restrict__ k_w,
    const float* __restrict__ v_w, const float* __restrict__ out_w,
    const float* __restrict__ sp_w, const float* __restrict__ amp_w,
    const float* __restrict__ ph_w,
    short* __restrict__ dst)
{
    int i = blockIdx.x*256 + threadIdx.x;   // 90112 total
    float v;
    if      (i < 16384) v = q_w[i];
    else if (i < 32768) v = k_w[i-16384];
    else if (i < 49152) v = v_w[i-32768];
    else if (i < 65536) v = out_w[i-49152];
    else if (i < 81920) v = sp_w[i-65536];
    else if (i < 86016) v = amp_w[i-81920];
    else                v = ph_w[i-86016];
    dst[i] = f2bf(v);
}

// ---------------- Combined measurement weights: Wc = meas_w @ ent_w (fold ENT into MEAS) ----------------
// mi[e][kk][o] = cat[e] @ Wci[kk][o][:] + bci[kk][o]   (ei = ent rows 0..127, ej = rows 128..255)
__global__ __launch_bounds__(256) void combine_kernel(
    const float* __restrict__ ent_w, const float* __restrict__ meas_w,
    short* __restrict__ wCi, short* __restrict__ wCj)
{
    const int b = blockIdx.x;          // 512 blocks
    const int kk = b >> 7, half = (b >> 6) & 1, ot = (b >> 3) & 7, ct = b & 7;
    const int tid = threadIdx.x;
    const int o = ot*16 + (tid >> 4);
    const int c = ct*32 + (tid & 15)*2;
    const float* mrow  = meas_w + ((long)(kk*128 + o) << 7);
    const float* wbase = ent_w + (long)(half*128)*256 + c;
    float a0 = 0.f, a1 = 0.f;
    #pragma unroll 8
    for (int k = 0; k < 128; k++){
        float m = mrow[k];
        float2 wv = *(const float2*)(wbase + (long)k*256);
        a0 = fmaf(m, wv.x, a0);
        a1 = fmaf(m, wv.y, a1);
    }
    short* dst = (half ? wCj : wCi) + (long)kk*32768 + o*256 + c;
    dst[0] = f2bf(a0); dst[1] = f2bf(a1);
}
__global__ __launch_bounds__(256) void combine_bias_kernel(
    const float* __restrict__ meas_w, const float* __restrict__ ent_b,
    const float* __restrict__ meas_b,
    float* __restrict__ bci, float* __restrict__ bcj)
{
    int id = blockIdx.x*256 + threadIdx.x;  // 1024
    int kk = id >> 8, half = (id >> 7) & 1, o = id & 127;
    const float* mrow = meas_w + ((long)(kk*128 + o) << 7);
    const float* eb = ent_b + half*128;
    float a = meas_b[kk*128 + o];
    #pragma unroll 8
    for (int k = 0; k < 128; k++) a = fmaf(mrow[k], eb[k], a);
    (half ? bcj : bci)[kk*128 + o] = a;
}

// ---------------- Sort pipeline: counting sort of edges by tgt ----------------
__global__ __launch_bounds__(256) void hist_kernel(const int* __restrict__ eidx, int* __restrict__ hist){
    int i = blockIdx.x*256 + threadIdx.x;
    if (i < EE) atomicAdd(&hist[eidx[EE+i]], 1);
}
__global__ __launch_bounds__(512) void scanA_kernel(const int* __restrict__ hist,
                                                    int* __restrict__ scanv, int* __restrict__ bsum){
    __shared__ int s[512];
    const int tid = threadIdx.x;
    const int i = blockIdx.x*512 + tid;
    int v = hist[i];
    s[tid] = v;
    __syncthreads();
    #pragma unroll
    for (int d=1; d<512; d<<=1){
        int t = (tid>=d) ? s[tid-d] : 0;
        __syncthreads();
        s[tid] += t;
        __syncthreads();
    }
    scanv[i] = s[tid] - v;
    if (tid==511) bsum[blockIdx.x] = s[511];
}
__global__ __launch_bounds__(256) void scanB_kernel(const int* __restrict__ bsum, int* __restrict__ boff){
    __shared__ int s[256];
    const int tid = threadIdx.x;
    int v = (tid<196) ? bsum[tid] : 0;
    s[tid] = v;
    __syncthreads();
    #pragma unroll
    for (int d=1; d<256; d<<=1){
        int t = (tid>=d) ? s[tid-d] : 0;
        __syncthreads();
        s[tid] += t;
        __syncthreads();
    }
    if (tid<196) boff[tid] = s[tid] - v;
}
__global__ __launch_bounds__(256) void scatter_kernel(const int* __restrict__ eidx,
    const int* __restrict__ scanv, const int* __restrict__ boff, int* __restrict__ cnt,
    int* __restrict__ sTgt, int* __restrict__ sSrc)
{
    int i = blockIdx.x*256 + threadIdx.x;
    if (i >= EE) return;
    int t = eidx[EE+i], sv = eidx[i];
    int r = atomicAdd(&cnt[t], 1);
    int pos = scanv[t] + boff[t>>9] + r;
    sTgt[pos] = t; sSrc[pos] = sv;
}

// ---------------- Stage 1: node prep via MFMA, 64 nodes/block ----------------
__global__ __launch_bounds__(512) void node_kernel(
    const float* __restrict__ x,
    const short* __restrict__ wSP, const float* __restrict__ sp_b,
    const float* __restrict__ ln1_g, const float* __restrict__ ln1_b,
    const float* __restrict__ pg,
    const short* __restrict__ wA, const float* __restrict__ amp_b,
    const short* __restrict__ wP, const float* __restrict__ ph_b,
    short* __restrict__ qfb)
{
    __shared__ short xb[64*128];     // bf16, swizzled C16 (16 KB)
    __shared__ float yb[64*132];     // f32 GEMM out / later amp|ph (33.8 KB)
    __shared__ short qsb[64*128];    // bf16 tanh(LN(y)), swizzled (16 KB)
    __shared__ float pgs[64];

    const int tid = threadIdx.x;
    const int lane = tid & 63;
    const int w    = tid >> 6;
    const int l15  = lane & 15;
    const int lj   = (lane >> 4) << 2;
    const int n0   = blockIdx.x * 64;

    if (tid < 64){
        float s = 0.f;
        #pragma unroll
        for (int r=0;r<8;r++) s += pg[r*64 + tid];
        pgs[tid] = s;
    }
    for (int t = tid; t < 1024; t += 512){
        int e = t >> 4, c8 = t & 15;
        int n = n0 + e; if (n >= NN) n = NN-1;
        const float4* xg = (const float4*)(x + (long)n*128 + c8*8);
        float4 a = xg[0], b = xg[1];
        short8 sv;
        sv[0]=f2bf(a.x); sv[1]=f2bf(a.y); sv[2]=f2bf(a.z); sv[3]=f2bf(a.w);
        sv[4]=f2bf(b.x); sv[5]=f2bf(b.y); sv[6]=f2bf(b.z); sv[7]=f2bf(b.w);
        ((short8*)xb)[C16(e, c8)] = sv;
    }
    __syncthreads();

    const short8* xbv = (const short8*)xb;
    const int col = (w<<4) + l15;

    {
        f32x4 acc[4];
        #pragma unroll
        for (int r=0;r<4;r++) acc[r]=(f32x4){0,0,0,0};
        #pragma unroll
        for (int ks=0; ks<4; ks++){
            short8 bw = bfrag(wSP,128,w,ks,lane);
            #pragma unroll
            for (int r=0;r<4;r++){
                int row = r*16+l15;
                acc[r] = mfma16(xbv[(row<<4) + (((ks<<2)+(lane>>4)) ^ (row&7))], bw, acc[r]);
            }
        }
        float bias = sp_b[col];
        #pragma unroll
        for (int r=0;r<4;r++){
            #pragma unroll
            for (int j=0;j<4;j++)
                yb[(r*16+lj+j)*132 + col] = acc[r][j] + bias;
        }
    }
    __syncthreads();

    {
        const int row = tid >> 3, cs = tid & 7;
        float v[16];
        float s = 0.f, sq = 0.f;
        #pragma unroll
        for (int i=0;i<16;i++){
            v[i] = yb[row*132 + cs*16 + i];
            s += v[i]; sq += v[i]*v[i];
        }
        #pragma unroll
        for (int m=1;m<8;m<<=1){ s += __shfl_xor(s,m); sq += __shfl_xor(sq,m); }
        float mean = s*(1.0f/128.0f);
        float rstd = rsqrtf(sq*(1.0f/128.0f) - mean*mean + 1e-5f);
        short8 s0, s1;
        #pragma unroll
        for (int i=0;i<16;i++){
            int c = cs*16 + i;
            float q = tanhf((v[i]-mean)*rstd*ln1_g[c] + ln1_b[c]);
            if (i<8) s0[i] = f2bf(q); else s1[i-8] = f2bf(q);
        }
        ((short8*)qsb)[C16(row, cs*2  )] = s0;
        ((short8*)qsb)[C16(row, cs*2+1)] = s1;
    }
    __syncthreads();

    {
        const short8* qv = (const short8*)qsb;
        const int isPh = w >> 2;
        const int ct   = w & 3;
        f32x4 a4[4];
        #pragma unroll
        for (int r=0;r<4;r++) a4[r]=(f32x4){0,0,0,0};
        #pragma unroll
        for (int ks=0; ks<2; ks++){
            short8 bw = bfrag(isPh ? wP : wA, 64, ct, ks, lane);
            #pragma unroll
            for (int r=0;r<4;r++){
                int row = r*16+l15;
                int ch = isPh*8 + (ks<<2)+(lane>>4);
                a4[r] = mfma16(qv[(row<<4) + (ch ^ (row&7))], bw, a4[r]);
            }
        }
        const int oc = ct*16 + l15;
        float bs = isPh ? ph_b[oc] : amp_b[oc];
        #pragma unroll
        for (int r=0;r<4;r++){
            #pragma unroll
            for (int j=0;j<4;j++){
                float vv = a4[r][j] + bs;
                float ov = isPh ? tanhf(vv)*3.14159265358979323846f
                                : 1.0f/(1.0f+expf(-vv));
                yb[(r*16+lj+j)*132 + isPh*64 + oc] = ov;
            }
        }
    }
    __syncthreads();

    {
        const int row = tid >> 3, cs = tid & 7;
        const int n = n0 + row;
        short8 outc, outs;
        #pragma unroll
        for (int i=0;i<8;i++){
            int c = cs*8 + i;
            float amp  = yb[row*132 + c];
            float ph   = yb[row*132 + 64 + c];
            float real = bf2f(qsb[E16(row, c)]);
            float ang  = ph + real*pgs[c];
            outc[i] = f2bf(amp * cosf(ang));
            outs[i] = f2bf(amp * sinf(ang));
        }
        if (n < NN){
            *(short8*)(qfb + (long)n*128 + cs*8)      = outc;
            *(short8*)(qfb + (long)n*128 + 64 + cs*8) = outs;
        }
    }
}

// ---------------- Stage 2: per-edge MFMA message; 5 barriers, no score/ENT phases ----------------
__global__ __launch_bounds__(512) void edge_kernel(
    const short* __restrict__ qfb,
    const int* __restrict__ sTgt, const int* __restrict__ sSrc,
    const short* __restrict__ wQ, const float* __restrict__ q_b,
    const short* __restrict__ wK, const float* __restrict__ k_b,
    const short* __restrict__ wV, const float* __restrict__ v_b,
    const short* __restrict__ wCi, const float* __restrict__ bci,
    const short* __restrict__ wCj, const float* __restrict__ bcj,
    const short* __restrict__ wO, const float* __restrict__ out_b,
    float* __restrict__ agg)
{
    __shared__ short xin[ET*256];      // 32 KB, C32-swizzled; later msgF f32 [64][128] XOR-swz
    __shared__ short msgb[ET*128];     // 16 KB, C16-swizzled
    __shared__ float part[ET][9];      // q·k per-strip partials
    __shared__ float swv[ET][5];       // softmax weights
    __shared__ int tg[ET], srr[ET];
    __shared__ int tgPrevS, tgNextS;
    float* msgF = (float*)xin;

    // bijective XCD-chunked swizzle (m204)
    const int nwg = gridDim.x, orig = blockIdx.x;
    const int qd = nwg>>3, rm = nwg&7, xc = orig&7, oo = orig>>3;
    const int bid = (xc<rm ? xc*(qd+1) : rm*(qd+1)+(xc-rm)*qd) + oo;

    const int tid  = threadIdx.x;
    const int lane = tid & 63;
    const int w    = tid >> 6;
    const long e0  = (long)bid * ET;
    const int l15  = lane & 15;
    const int lj   = (lane >> 4) << 2;
    const int col  = (w<<4) + l15;

    if (tid < ET) { tg[tid] = sTgt[e0+tid]; srr[tid] = sSrc[e0+tid]; }
    if (tid == 64) tgPrevS = (e0 > 0)      ? sTgt[e0-1]  : -2;
    if (tid == 65) tgNextS = (e0+ET < NPAD)? sTgt[e0+ET] : -2;
    __syncthreads();

    for (int t = tid; t < ET*32; t += 512) {
        int e = t >> 5, c8 = t & 31;
        int node = (c8 < 16) ? tg[e] : srr[e];
        if (node < 0) node = 0;
        short8 val = ((const short8*)(qfb + (long)node*128))[c8 & 15];
        ((short8*)xin)[C32(e, c8)] = val;
    }
    __syncthreads();                   // S1

    const short8* xinv = (const short8*)xin;

    // ---- Q,K in registers; scores via in-wave reduce -> part ----
    {
        f32x4 aq[4], ak[4];
        #pragma unroll
        for (int r=0;r<4;r++){ aq[r]=(f32x4){0,0,0,0}; ak[r]=(f32x4){0,0,0,0}; }
        #pragma unroll
        for (int ks=0; ks<4; ks++){
            short8 bq = bfrag(wQ,128,w,ks,lane);
            short8 bk = bfrag(wK,128,w,ks,lane);
            #pragma unroll
            for (int r=0;r<4;r++){
                short8 ai = xinv[C32(r*16+l15, (ks<<2)+(lane>>4))];
                short8 aj = xinv[C32(r*16+l15, 16+(ks<<2)+(lane>>4))];
                aq[r] = mfma16(ai, bq, aq[r]);
                ak[r] = mfma16(aj, bk, ak[r]);
            }
        }
        float qb_ = q_b[col], kb_ = k_b[col];
        float p[4][4];
        #pragma unroll
        for (int r=0;r<4;r++){
            #pragma unroll
            for (int j=0;j<4;j++)
                p[r][j] = (aq[r][j]+qb_)*(ak[r][j]+kb_);
        }
        #pragma unroll
        for (int m=1;m<16;m<<=1){
            #pragma unroll
            for (int r=0;r<4;r++){
                #pragma unroll
                for (int j=0;j<4;j++)
                    p[r][j] += __shfl_xor(p[r][j], m);
            }
        }
        if (l15 == 0){
            #pragma unroll
            for (int r=0;r<4;r++){
                #pragma unroll
                for (int j=0;j<4;j++)
                    part[r*16+lj+j][w] = p[r][j];
            }
        }
    }
    __syncthreads();                   // S2

    // ---- softmax (tid<64) hidden under V MFMAs (all threads) ----
    if (tid < 64){
        const float sc = 0.17677669529663688f;   // 1/sqrt(32)
        float s0 = (part[tid][0]+part[tid][1]) * sc;
        float s1 = (part[tid][2]+part[tid][3]) * sc;
        float s2 = (part[tid][4]+part[tid][5]) * sc;
        float s3 = (part[tid][6]+part[tid][7]) * sc;
        float mx = fmaxf(fmaxf(s0,s1),fmaxf(s2,s3));
        s0=expf(s0-mx); s1=expf(s1-mx); s2=expf(s2-mx); s3=expf(s3-mx);
        float inv = 1.0f/(s0+s1+s2+s3);
        swv[tid][0]=s0*inv; swv[tid][1]=s1*inv; swv[tid][2]=s2*inv; swv[tid][3]=s3*inv;
    }
    f32x4 av[4];
    {
        #pragma unroll
        for (int r=0;r<4;r++) av[r]=(f32x4){0,0,0,0};
        #pragma unroll
        for (int ks=0; ks<4; ks++){
            short8 bv = bfrag(wV,128,w,ks,lane);
            #pragma unroll
            for (int r=0;r<4;r++)
                av[r] = mfma16(xinv[C32(r*16+l15, 16+(ks<<2)+(lane>>4))], bv, av[r]);
        }
    }
    __syncthreads();                   // S3

    // ---- qm = swv*(v+b); MEAS via combined weights (A-frags from xin) ----
    f32x4 qm[4];
    {
        float vb_ = v_b[col];
        const int h = w >> 1;
        #pragma unroll
        for (int r=0;r<4;r++){
            #pragma unroll
            for (int j=0;j<4;j++)
                qm[r][j] = (av[r][j] + vb_) * swv[r*16+lj+j][h];
        }
    }
    #pragma unroll 1
    for (int kk=0; kk<4; kk++){
        f32x4 mi[4], mj[4];
        #pragma unroll
        for (int r=0;r<4;r++){ mi[r]=(f32x4){0,0,0,0}; mj[r]=(f32x4){0,0,0,0}; }
        const short* wci = wCi + (long)kk*32768;
        const short* wcj = wCj + (long)kk*32768;
        #pragma unroll
        for (int ks=0; ks<8; ks++){
            short8 bi = bfrag(wci,256,w,ks,lane);
            short8 bj = bfrag(wcj,256,w,ks,lane);
            #pragma unroll
            for (int r=0;r<4;r++){
                short8 a = xinv[C32(r*16+l15, (ks<<2)+(lane>>4))];
                mi[r] = mfma16(a, bi, mi[r]);
                mj[r] = mfma16(a, bj, mj[r]);
            }
        }
        float bi_ = bci[kk*128+col], bj_ = bcj[kk*128+col];
        #pragma unroll
        for (int r=0;r<4;r++){
            #pragma unroll
            for (int j=0;j<4;j++)
                qm[r][j] += 0.25f*(mi[r][j]+bi_)*(mj[r][j]+bj_);
        }
    }
    // ---- write msg-in bf16 (separate region, no extra barrier needed) ----
    {
        #pragma unroll
        for (int r=0;r<4;r++){
            #pragma unroll
            for (int j=0;j<4;j++){
                int row = r*16 + lj + j;
                int ch = (col>>3) ^ (row&7);
                msgb[((row<<4)+ch)*8 + (col&7)] = f2bf(qm[r][j]);
            }
        }
    }
    __syncthreads();                   // S4

    // ---- OUT: msg = msgb@Wo^T + b -> msgF (f32, XOR-swizzled, overlays xin) ----
    {
        const short8* mv = (const short8*)msgb;
        f32x4 ao[4];
        #pragma unroll
        for (int r=0;r<4;r++) ao[r]=(f32x4){0,0,0,0};
        #pragma unroll
        for (int ks=0; ks<4; ks++){
            short8 bo = bfrag(wO,128,w,ks,lane);
            #pragma unroll
            for (int r=0;r<4;r++){
                int row = r*16+l15;
                int ch = ((ks<<2)+(lane>>4)) ^ (row&7);
                ao[r] = mfma16(mv[(row<<4)+ch], bo, ao[r]);
            }
        }
        float ob = out_b[col];
        #pragma unroll
        for (int r=0;r<4;r++){
            #pragma unroll
            for (int j=0;j<4;j++){
                int row = r*16 + lj + j;
                msgF[(row<<7) + (col ^ (row&31))] = ao[r][j] + ob;
            }
        }
    }
    __syncthreads();                   // S5

    // ---- per-tile segmented reduction over sorted tgt runs ----
    if (tid < 128){
        const int c = tid;
        const int tgPrev = tgPrevS, tgNext = tgNextS;
        float acc = 0.f;
        int runStart = 0;
        #pragma unroll 4
        for (int r=0; r<ET; r++){
            acc += msgF[(r<<7) + (c ^ (r&31))];
            bool last = (r==ET-1) || (tg[r+1] != tg[r]);
            if (last){
                int node = tg[r];
                if (node >= 0){
                    bool openL = (runStart==0) && (tgPrev == node);
                    bool openR = (r==ET-1)     && (tgNext == node);
                    if (openL || openR) atomicAdd(&agg[(long)node*128 + c], acc);
                    else                agg[(long)node*128 + c] = acc;
                }
                acc = 0.f; runStart = r+1;
            }
        }
    }
}

// ---------------- Stage 3: LN + exact gelu, in place on d_out ----------------
__global__ __launch_bounds__(256) void final_kernel(
    const float* __restrict__ g2, const float* __restrict__ b2,
    float* __restrict__ io)
{
    const int lane = threadIdx.x & 63;
    const int n = blockIdx.x*4 + (threadIdx.x>>6);
    float v0 = io[(long)n*128 + lane];
    float v1 = io[(long)n*128 + 64 + lane];
    float s = v0+v1, sq = v0*v0 + v1*v1;
    #pragma unroll
    for (int m=1;m<64;m<<=1){ s += __shfl_xor(s,m); sq += __shfl_xor(sq,m); }
    float mean = s*(1.0f/128.0f);
    float rstd = rsqrtf(sq*(1.0f/128.0f)-mean*mean+1e-5f);
    float y0 = (v0-mean)*rstd*g2[lane]    + b2[lane];
    float y1 = (v1-mean)*rstd*g2[64+lane] + b2[64+lane];
    io[(long)n*128+lane]    = 0.5f*y0*(1.0f+erff(y0*0.70710678118f));
    io[(long)n*128+64+lane] = 0.5f*y1*(1.0f+erff(y1*0.70710678118f));
}

extern "C" void kernel_launch(void* const* d_in, const int* in_sizes, int n_in,
                              void* d_out, int out_size, void* d_ws, size_t ws_size,
                              hipStream_t stream)
{
    const float* x      = (const float*)d_in[0];
    const int*   eidx   = (const int*)  d_in[1];
    const float* sp_w   = (const float*)d_in[2];
    const float* sp_b   = (const float*)d_in[3];
    const float* ln1_g  = (const float*)d_in[4];
    const float* ln1_b  = (const float*)d_in[5];
    const float* pg     = (const float*)d_in[6];
    const float* amp_w  = (const float*)d_in[7];
    const float* amp_b  = (const float*)d_in[8];
    const float* ph_w   = (const float*)d_in[9];
    const float* ph_b   = (const float*)d_in[10];
    const float* ent_w  = (const float*)d_in[11];
    const float* ent_b  = (const float*)d_in[12];
    const float* q_w    = (const float*)d_in[13];
    const float* q_b    = (const float*)d_in[14];
    const float* k_w    = (const float*)d_in[15];
    const float* k_b    = (const float*)d_in[16];
    const float* v_w    = (const float*)d_in[17];
    const float* v_b    = (const float*)d_in[18];
    const float* meas_w = (const float*)d_in[19];
    const float* meas_b = (const float*)d_in[20];
    const float* out_w  = (const float*)d_in[21];
    const float* out_b  = (const float*)d_in[22];
    const float* ln2_g  = (const float*)d_in[23];
    const float* ln2_b  = (const float*)d_in[24];

    char* wsb = (char*)d_ws;
    short* qfb  = (short*)wsb;                      // 25,600,000 B
    short* wAll = (short*)(wsb + 25600000);         //   180,224 B
    short* wCi  = (short*)(wsb + 25780224);         //   262,144 B
    short* wCj  = (short*)(wsb + 26042368);         //   262,144 B
    float* bci  = (float*)(wsb + 26304512);         //     2,048 B
    float* bcj  = (float*)(wsb + 26306560);         //     2,048 B
    int* hist   = (int*)(wsb + 26308608);           //   401,408 B
    int* cnt    = (int*)(wsb + 26710016);           //   401,408 B
    int* scanv  = (int*)(wsb + 27111424);           //   401,408 B
    int* bsum   = (int*)(wsb + 27512832);           //     1,024 B
    int* boff   = (int*)(wsb + 27513856);           //     1,024 B
    int* sTgt   = (int*)(wsb + 27514880);           // 2,000,128 B
    int* sSrc   = (int*)(wsb + 29515008);           // 2,000,128 B -> 31.5 MB

    short* wQ  = wAll;
    short* wK  = wAll + 16384;
    short* wV  = wAll + 32768;
    short* wO  = wAll + 49152;
    short* wSP = wAll + 65536;
    short* wA  = wAll + 81920;
    short* wP  = wAll + 86016;

    float* agg = (float*)d_out;

    hipMemsetAsync(d_out, 0, (size_t)NN*128*sizeof(float), stream);
    hipMemsetAsync(hist, 0, 401408, stream);
    hipMemsetAsync(cnt,  0, 401408, stream);
    hipMemsetAsync(sTgt + EE, 0xFF, (NPAD-EE)*sizeof(int), stream);   // pad tgt = -1
    hipMemsetAsync(sSrc + EE, 0x00, (NPAD-EE)*sizeof(int), stream);

    prep_kernel<<<352, 256, 0, stream>>>(q_w, k_w, v_w, out_w, sp_w, amp_w, ph_w, wAll);
    combine_kernel<<<512, 256, 0, stream>>>(ent_w, meas_w, wCi, wCj);
    combine_bias_kernel<<<4, 256, 0, stream>>>(meas_w, ent_b, meas_b, bci, bcj);
    node_kernel<<<NNB, 512, 0, stream>>>(x, wSP, sp_b, ln1_g, ln1_b, pg,
                                         wA, amp_b, wP, ph_b, qfb);
    hist_kernel<<<(EE+255)/256, 256, 0, stream>>>(eidx, hist);
    scanA_kernel<<<196, 512, 0, stream>>>(hist, scanv, bsum);
    scanB_kernel<<<1, 256, 0, stream>>>(bsum, boff);
    scatter_kernel<<<(EE+255)/256, 256, 0, stream>>>(eidx, scanv, boff, cnt, sTgt, sSrc);
    edge_kernel<<<NEB, 512, 0, stream>>>(qfb, sTgt, sSrc,
                                         wQ, q_b, wK, k_b, wV, v_b,
                                         wCi, bci, wCj, bcj, wO, out_b, agg);
    final_kernel<<<NN/4, 256, 0, stream>>>(ln2_g, ln2_b, agg);
}